// Round 9
// baseline (4037.229 us; speedup 1.0000x reference)
//
#include <hip/hip_runtime.h>
#include <hip/hip_bf16.h>
#include <stdint.h>

typedef __hip_bfloat16 bf16;

#define EPSBN 1e-5f
#define CHUNK 14080      // edges per k_bucket WG (56320 B LDS staging)
#define BSH   9          // 512-node buckets
#define BCAP  22528      // per-bucket padded capacity
#define SUBCAP 5632      // BCAP/4: per-128-node sub-bucket capacity (avg 4092, +24 sigma)
#define SENT  0xFFFFFFFFu

__device__ __forceinline__ float bits2f(unsigned int u) { return __uint_as_float(u); }

__device__ __forceinline__ void atomAddF(float* p, float v) {
#if defined(__HIP_DEVICE_COMPILE__)
    unsafeAtomicAdd(p, v);   // native global_atomic_add_f32 on gfx950
#else
    atomicAdd(p, v);
#endif
}

// ---- per-graph node counts ----
__global__ __launch_bounds__(256) void k_cntg(const int* __restrict__ batch,
                                              int* __restrict__ cntg, int n) {
    int i = blockIdx.x * 256 + threadIdx.x;
    if (i < n) atomicAdd(&cntg[batch[i]], 1);
}

// ======== CSR phase 1: LDS counting-sort per chunk, coalesced padded flush ====
__global__ __launch_bounds__(512) void k_bucket(const int* __restrict__ ei, int E,
                                                int* __restrict__ bcntP,
                                                unsigned int* __restrict__ pairT,
                                                int NB) {
    __shared__ unsigned int stage[CHUNK];
    __shared__ int cR[512];
    __shared__ int lbase[512];
    __shared__ int gpos[512];
    __shared__ int lhead[512];
    int t = threadIdx.x;
    int e0 = blockIdx.x * CHUNK;
    int e1 = e0 + CHUNK; if (e1 > E) e1 = E;
    const int* dst = ei + E;

    cR[t] = 0; lhead[t] = 0;
    __syncthreads();
    for (int e = e0 + t; e < e1; e += 512) atomicAdd(&cR[dst[e] >> BSH], 1);
    __syncthreads();
    int c = cR[t];
    lbase[t] = c;
    __syncthreads();
    for (int off = 1; off < 512; off <<= 1) {
        int u = (t >= off) ? lbase[t - off] : 0;
        __syncthreads();
        lbase[t] += u;
        __syncthreads();
    }
    lbase[t] -= c;
    if (t < NB && c > 0) {
        int p16 = (c + 15) & ~15;
        gpos[t] = atomicAdd(&bcntP[t], p16);
    } else {
        gpos[t] = 0;
    }
    __syncthreads();
    for (int e = e0 + t; e < e1; e += 512) {
        int s = ei[e], d = dst[e];
        int b = d >> BSH;
        int pos = atomicAdd(&lhead[b], 1);
        stage[lbase[b] + pos] = (unsigned int)s | ((unsigned int)(d & 511) << 18);
    }
    __syncthreads();
    int wave = t >> 6, lane = t & 63;
    for (int b = wave; b < NB; b += 8) {
        int cc = cR[b];
        if (cc == 0) continue;
        int p16 = (cc + 15) & ~15;
        int lb = lbase[b];
        size_t gb = (size_t)b * BCAP + gpos[b];
        for (int j = lane; j < p16; j += 64) {
            unsigned int v = (j < cc) ? stage[lb + j] : SENT;
            if (gpos[b] + j < BCAP) pairT[gb + j] = v;
        }
    }
}

// ======== phase 2: per-bucket — degree->dinv; sort edges by (sub128, src-slice) ====
// Output: 4 compact sub-lists per bucket at b*BCAP + sub*SUBCAP, counts in cnt4.
__global__ __launch_bounds__(512) void k_slice(const unsigned int* __restrict__ pairT,
                                               const int* __restrict__ bcntP,
                                               unsigned int* __restrict__ edgesS,
                                               int* __restrict__ cnt4,
                                               float* __restrict__ dinv, int n) {
    __shared__ int h[64];    // bins: sub(2b)*16 + slice(src>>14, <16)
    __shared__ int deg[512];
    int b = blockIdx.x, t = threadIdx.x;
    if (t < 64) h[t] = 0;
    deg[t] = 0;
    __syncthreads();
    int m = min(bcntP[b], BCAP);
    const unsigned int* P = pairT + (size_t)b * BCAP;
    for (int i = t; i < m; i += 512) {
        unsigned int v = P[i];
        if (v != SENT) {
            int dloc = (int)(v >> 18);
            int s = (int)(v & 0x3FFFFu);
            atomicAdd(&deg[dloc], 1);
            atomicAdd(&h[(dloc >> 7) * 16 + (s >> 14)], 1);
        }
    }
    __syncthreads();
    int bn0 = b << BSH;
    if (bn0 + t < n) dinv[bn0 + t] = rsqrtf((float)(deg[t] + 1));  // + self-loop
    if (t == 0) {
        for (int sub = 0; sub < 4; ++sub) {
            int acc = sub * SUBCAP, tot = 0;
            for (int sl = 0; sl < 16; ++sl) {
                int c = h[sub * 16 + sl];
                h[sub * 16 + sl] = acc;
                acc += c; tot += c;
            }
            cnt4[b * 4 + sub] = min(tot, SUBCAP);
        }
    }
    __syncthreads();
    for (int i = t; i < m; i += 512) {
        unsigned int v = P[i];
        if (v != SENT) {
            int dloc = (int)(v >> 18);
            int s = (int)(v & 0x3FFFFu);
            int sub = dloc >> 7;
            int pos = atomicAdd(&h[sub * 16 + (s >> 14)], 1);
            if (pos < (sub + 1) * SUBCAP)
                edgesS[(size_t)b * BCAP + pos] = v;
        }
    }
}

// ======== GEMMs (Y = bf16(dinv * (X @ W)), BN affine folded for 32-wide) ====

__global__ __launch_bounds__(256) void k_gemm1(const float* __restrict__ x,
                                               const float* __restrict__ W,
                                               const float* __restrict__ dinv,
                                               bf16* __restrict__ Y, int n) {
    __shared__ float Ws[128 * 32];
    __shared__ float xs[32 * 128];
    int tid = threadIdx.x;
    int base = blockIdx.x * 32;
    for (int i = tid; i < 128 * 32; i += 256) Ws[i] = W[i];
    if (base + 32 <= n) {
        const float4* x4 = (const float4*)(x + (size_t)base * 128);
        for (int i = tid; i < 1024; i += 256) {
            float4 v = x4[i];
            xs[i * 4 + 0] = v.x; xs[i * 4 + 1] = v.y;
            xs[i * 4 + 2] = v.z; xs[i * 4 + 3] = v.w;
        }
    } else {
        for (int i = tid; i < 32 * 128; i += 256) {
            int r = i >> 7, c = i & 127;
            int row = base + r;
            xs[i] = (row < n) ? x[(size_t)row * 128 + c] : 0.f;
        }
    }
    __syncthreads();
    int r0 = tid >> 5, j = tid & 31;
    float a0 = 0.f, a1 = 0.f, a2 = 0.f, a3 = 0.f;
#pragma unroll 8
    for (int k = 0; k < 128; ++k) {
        float w = Ws[k * 32 + j];
        a0 = fmaf(xs[(r0     ) * 128 + k], w, a0);
        a1 = fmaf(xs[(r0 +  8) * 128 + k], w, a1);
        a2 = fmaf(xs[(r0 + 16) * 128 + k], w, a2);
        a3 = fmaf(xs[(r0 + 24) * 128 + k], w, a3);
    }
    int row;
    row = base + r0;      if (row < n) Y[(size_t)row * 32 + j] = __float2bfloat16(a0 * dinv[row]);
    row = base + r0 + 8;  if (row < n) Y[(size_t)row * 32 + j] = __float2bfloat16(a1 * dinv[row]);
    row = base + r0 + 16; if (row < n) Y[(size_t)row * 32 + j] = __float2bfloat16(a2 * dinv[row]);
    row = base + r0 + 24; if (row < n) Y[(size_t)row * 32 + j] = __float2bfloat16(a3 * dinv[row]);
}

__global__ __launch_bounds__(256) void k_gemm32(const float* __restrict__ H,
                                                const float* __restrict__ W,
                                                const float* __restrict__ scale,
                                                const float* __restrict__ shift,
                                                const float* __restrict__ dinv,
                                                bf16* __restrict__ Y, int n) {
    __shared__ float Ws[32 * 32];
    __shared__ float xs[32 * 32];
    int tid = threadIdx.x;
    int base = blockIdx.x * 32;
    for (int i = tid; i < 1024; i += 256) Ws[i] = W[i];
    for (int i = tid; i < 1024; i += 256) {
        int r = i >> 5, k = i & 31;
        int row = base + r;
        xs[i] = (row < n) ? fmaf(H[(size_t)row * 32 + k], scale[k], shift[k]) : 0.f;
    }
    __syncthreads();
    int r0 = tid >> 5, j = tid & 31;
    float a0 = 0.f, a1 = 0.f, a2 = 0.f, a3 = 0.f;
#pragma unroll
    for (int k = 0; k < 32; ++k) {
        float w = Ws[k * 32 + j];
        a0 = fmaf(xs[(r0     ) * 32 + k], w, a0);
        a1 = fmaf(xs[(r0 +  8) * 32 + k], w, a1);
        a2 = fmaf(xs[(r0 + 16) * 32 + k], w, a2);
        a3 = fmaf(xs[(r0 + 24) * 32 + k], w, a3);
    }
    int row;
    row = base + r0;      if (row < n) Y[(size_t)row * 32 + j] = __float2bfloat16(a0 * dinv[row]);
    row = base + r0 + 8;  if (row < n) Y[(size_t)row * 32 + j] = __float2bfloat16(a1 * dinv[row]);
    row = base + r0 + 16; if (row < n) Y[(size_t)row * 32 + j] = __float2bfloat16(a2 * dinv[row]);
    row = base + r0 + 24; if (row < n) Y[(size_t)row * 32 + j] = __float2bfloat16(a3 * dinv[row]);
}

// ======== LDS-AGG aggregation + tanh + BN stats (layers 1,2) ========
// WG = 128-node sub-bucket. AGG[128][33] fp32 in LDS. One lane per edge:
// 4x uint4 loads of Y row (slice-sorted => L2-resident) + 32 ds_add_f32.
__global__ __launch_bounds__(256) void k_agg_bn(const unsigned int* __restrict__ edgesS,
                                                const int* __restrict__ cnt4,
                                                const bf16* __restrict__ Y,
                                                const float* __restrict__ dinv,
                                                const float* __restrict__ bias,
                                                float* __restrict__ H,
                                                float* __restrict__ stats, int n) {
    __shared__ float AGG[128 * 33];
    __shared__ float rsA[32], rs2A[32];
    int bi = blockIdx.x;
    int b = bi >> 2, sub = bi & 3;
    int bn0 = (b << BSH) + (sub << 7);
    int nn = n - bn0; nn = nn < 0 ? 0 : (nn > 128 ? 128 : nn);
    int t = threadIdx.x;
    for (int idx = t; idx < nn * 16; idx += 256) {      // self-loop init
        int r = idx >> 4, u = idx & 15;
        unsigned int v = ((const unsigned int*)(Y + ((size_t)(bn0 + r) << 5)))[u];
        AGG[r * 33 + u * 2]     = bits2f(v << 16);
        AGG[r * 33 + u * 2 + 1] = bits2f(v & 0xFFFF0000u);
    }
    if (t < 32) { rsA[t] = 0.f; rs2A[t] = 0.f; }
    __syncthreads();
    int m = (nn > 0) ? cnt4[bi] : 0;
    const unsigned int* EL = edgesS + (size_t)b * BCAP + (size_t)sub * SUBCAP;
    for (int i = t; i < m; i += 256) {
        unsigned int v = EL[i];
        int s = (int)(v & 0x3FFFFu);
        int dl = (int)((v >> 18) & 127u);
        const uint4* yr = (const uint4*)(Y + ((size_t)s << 5));
        float* A = &AGG[dl * 33];
#pragma unroll
        for (int k = 0; k < 4; ++k) {
            uint4 q = yr[k];
            atomicAdd(&A[k * 8 + 0], bits2f(q.x << 16));
            atomicAdd(&A[k * 8 + 1], bits2f(q.x & 0xFFFF0000u));
            atomicAdd(&A[k * 8 + 2], bits2f(q.y << 16));
            atomicAdd(&A[k * 8 + 3], bits2f(q.y & 0xFFFF0000u));
            atomicAdd(&A[k * 8 + 4], bits2f(q.z << 16));
            atomicAdd(&A[k * 8 + 5], bits2f(q.z & 0xFFFF0000u));
            atomicAdd(&A[k * 8 + 6], bits2f(q.w << 16));
            atomicAdd(&A[k * 8 + 7], bits2f(q.w & 0xFFFF0000u));
        }
    }
    __syncthreads();
    int f = t & 31;
    float bs = bias[f];
    float sA = 0.f, s2A = 0.f;
    for (int r = (t >> 5); r < nn; r += 8) {
        float h = tanhf(fmaf(dinv[bn0 + r], AGG[r * 33 + f], bs));
        H[((size_t)(bn0 + r) << 5) + f] = h;
        sA += h; s2A += h * h;
    }
    atomicAdd(&rsA[f], sA);
    atomicAdd(&rs2A[f], s2A);
    __syncthreads();
    if (t < 32 && nn > 0) {
        atomAddF(&stats[t], rsA[t]);
        atomAddF(&stats[32 + t], rs2A[t]);
    }
}

// ======== LDS-AGG aggregation + tanh + mean-pool (layer 3) ========
__global__ __launch_bounds__(256) void k_agg_pool(const unsigned int* __restrict__ edgesS,
                                                  const int* __restrict__ cnt4,
                                                  const bf16* __restrict__ Y,
                                                  const float* __restrict__ dinv,
                                                  const float* __restrict__ bias,
                                                  const int* __restrict__ batch,
                                                  float* __restrict__ pool, int n) {
    __shared__ float AGG[128 * 33];
    __shared__ float gpool[8 * 32];   // per-graph partials (batch sorted; ~2-3 graphs/block)
    int bi = blockIdx.x;
    int b = bi >> 2, sub = bi & 3;
    int bn0 = (b << BSH) + (sub << 7);
    int nn = n - bn0; nn = nn < 0 ? 0 : (nn > 128 ? 128 : nn);
    int t = threadIdx.x;
    for (int idx = t; idx < nn * 16; idx += 256) {
        int r = idx >> 4, u = idx & 15;
        unsigned int v = ((const unsigned int*)(Y + ((size_t)(bn0 + r) << 5)))[u];
        AGG[r * 33 + u * 2]     = bits2f(v << 16);
        AGG[r * 33 + u * 2 + 1] = bits2f(v & 0xFFFF0000u);
    }
    gpool[t] = 0.f;
    __syncthreads();
    int m = (nn > 0) ? cnt4[bi] : 0;
    const unsigned int* EL = edgesS + (size_t)b * BCAP + (size_t)sub * SUBCAP;
    for (int i = t; i < m; i += 256) {
        unsigned int v = EL[i];
        int s = (int)(v & 0x3FFFFu);
        int dl = (int)((v >> 18) & 127u);
        const uint4* yr = (const uint4*)(Y + ((size_t)s << 5));
        float* A = &AGG[dl * 33];
#pragma unroll
        for (int k = 0; k < 4; ++k) {
            uint4 q = yr[k];
            atomicAdd(&A[k * 8 + 0], bits2f(q.x << 16));
            atomicAdd(&A[k * 8 + 1], bits2f(q.x & 0xFFFF0000u));
            atomicAdd(&A[k * 8 + 2], bits2f(q.y << 16));
            atomicAdd(&A[k * 8 + 3], bits2f(q.y & 0xFFFF0000u));
            atomicAdd(&A[k * 8 + 4], bits2f(q.z << 16));
            atomicAdd(&A[k * 8 + 5], bits2f(q.z & 0xFFFF0000u));
            atomicAdd(&A[k * 8 + 6], bits2f(q.w << 16));
            atomicAdd(&A[k * 8 + 7], bits2f(q.w & 0xFFFF0000u));
        }
    }
    __syncthreads();
    int f = t & 31;
    float bs = bias[f];
    int g0 = (nn > 0) ? batch[bn0] : 0;
    for (int r = (t >> 5); r < nn; r += 8) {
        float h = tanhf(fmaf(dinv[bn0 + r], AGG[r * 33 + f], bs));
        int gl = batch[bn0 + r] - g0;
        if (gl < 8) atomicAdd(&gpool[gl * 32 + f], h);
        else        atomAddF(&pool[(size_t)batch[bn0 + r] * 32 + f], h);
    }
    __syncthreads();
    if (nn > 0) {
        float v = gpool[t];
        if (v != 0.f) atomAddF(&pool[(size_t)(g0 + (t >> 5)) * 32 + (t & 31)], v);
    }
}

// ---- finalize BN -> per-feature affine (scale, shift) ----
__global__ void k_bnfin(const float* __restrict__ stats, const float* __restrict__ g,
                        const float* __restrict__ be, float* __restrict__ scale,
                        float* __restrict__ shift, float invN) {
    int f = threadIdx.x;  // 32 threads
    float mu = stats[f] * invN;
    float var = stats[32 + f] * invN - mu * mu;
    float inv = rsqrtf(var + EPSBN);
    float sc = g[f] * inv;
    scale[f] = sc;
    shift[f] = be[f] - mu * sc;
}

// ---- head: out[g] = (pool[g]/cnt[g]) @ Wc + bc ----
__global__ __launch_bounds__(256) void k_final(const float* __restrict__ pool,
                                               const int* __restrict__ cntg,
                                               const float* __restrict__ Wc,
                                               const float* __restrict__ bc,
                                               float* __restrict__ out, int G) {
    int g = blockIdx.x * 256 + threadIdx.x;
    if (g >= G) return;
    float inv = 1.f / (float)max(cntg[g], 1);
    float acc = bc[0];
#pragma unroll
    for (int f = 0; f < 32; ++f) acc = fmaf(pool[(size_t)g * 32 + f] * inv, Wc[f], acc);
    out[g] = acc;
}

extern "C" void kernel_launch(void* const* d_in, const int* in_sizes, int n_in,
                              void* d_out, int out_size, void* d_ws, size_t ws_size,
                              hipStream_t stream) {
    const float* x    = (const float*)d_in[0];
    const int*   ei   = (const int*)d_in[1];
    const int*   batch= (const int*)d_in[2];
    const float* W1   = (const float*)d_in[3];
    const float* b1   = (const float*)d_in[4];
    const float* g1   = (const float*)d_in[5];
    const float* be1  = (const float*)d_in[6];
    const float* W2   = (const float*)d_in[7];
    const float* b2   = (const float*)d_in[8];
    const float* g2   = (const float*)d_in[9];
    const float* be2  = (const float*)d_in[10];
    const float* W3   = (const float*)d_in[11];
    const float* b3   = (const float*)d_in[12];
    // d_in[13], d_in[14] = g3, be3 (unused by reference)
    const float* Wc   = (const float*)d_in[15];
    const float* bc   = (const float*)d_in[16];
    float* out = (float*)d_out;

    const int n = in_sizes[0] / 128;   // 200000
    const int E = in_sizes[1] / 2;     // 6400000
    const int G = out_size;            // 2048
    const int NB = (n + 511) >> 9;     // 391 buckets of 512 nodes

    char* p = (char*)d_ws;
    auto alloc = [&p](size_t bytes) -> char* {
        uintptr_t q = ((uintptr_t)p + 255) & ~(uintptr_t)255;
        p = (char*)(q + bytes);
        return (char*)q;
    };
    // zero-initialized region first (contiguous from d_ws start)
    int*   cntg  = (int*)alloc((size_t)G * 4);
    float* stats = (float*)alloc(128 * 4);            // BN1: [0,64), BN2: [64,128)
    float* pool  = (float*)alloc((size_t)G * 32 * 4);
    int*   bcntP = (int*)alloc((size_t)NB * 4);       // padded reservations
    size_t zero_bytes = (size_t)(p - (char*)d_ws);
    float* dinv   = (float*)alloc((size_t)n * 4);
    float* scale1 = (float*)alloc(32 * 4);
    float* shift1 = (float*)alloc(32 * 4);
    float* scale2 = (float*)alloc(32 * 4);
    float* shift2 = (float*)alloc(32 * 4);
    int*   cnt4   = (int*)alloc((size_t)NB * 4 * 4);
    unsigned int* pairT  = (unsigned int*)alloc((size_t)NB * BCAP * 4);  // ~35 MB
    unsigned int* edgesS = (unsigned int*)alloc((size_t)NB * BCAP * 4);  // ~35 MB
    bf16*  bufY   = (bf16*)alloc((size_t)n * 32 * 2);
    float* bufH   = (float*)alloc((size_t)n * 32 * 4);

    hipMemsetAsync(d_ws, 0, zero_bytes, stream);

    int gN    = (n + 255) / 256;
    int gR32  = (n + 31) / 32;
    int gBuk  = (E + CHUNK - 1) / CHUNK;
    int gAgg  = NB * 4;
    float invN = 1.0f / (float)n;

    // ---- build sliced edge lists (once; shared by all 3 layers) ----
    k_cntg  <<<gN, 256, 0, stream>>>(batch, cntg, n);
    k_bucket<<<gBuk, 512, 0, stream>>>(ei, E, bcntP, pairT, NB);
    k_slice <<<NB, 512, 0, stream>>>(pairT, bcntP, edgesS, cnt4, dinv, n);

    // ---- layer 1 ----
    k_gemm1<<<gR32, 256, 0, stream>>>(x, W1, dinv, bufY, n);
    k_agg_bn<<<gAgg, 256, 0, stream>>>(edgesS, cnt4, bufY, dinv, b1, bufH, stats, n);
    k_bnfin<<<1, 32, 0, stream>>>(stats, g1, be1, scale1, shift1, invN);

    // ---- layer 2 ----
    k_gemm32<<<gR32, 256, 0, stream>>>(bufH, W2, scale1, shift1, dinv, bufY, n);
    k_agg_bn<<<gAgg, 256, 0, stream>>>(edgesS, cnt4, bufY, dinv, b2, bufH, stats + 64, n);
    k_bnfin<<<1, 32, 0, stream>>>(stats + 64, g2, be2, scale2, shift2, invN);

    // ---- layer 3 (tanh fused into pooling; no BN) ----
    k_gemm32<<<gR32, 256, 0, stream>>>(bufH, W3, scale2, shift2, dinv, bufY, n);
    k_agg_pool<<<gAgg, 256, 0, stream>>>(edgesS, cnt4, bufY, dinv, b3, batch, pool, n);

    // ---- head ----
    k_final<<<(G + 255) / 256, 256, 0, stream>>>(pool, cntg, Wc, bc, out, G);
}